// Round 12
// baseline (196.439 us; speedup 1.0000x reference)
//
#include <hip/hip_runtime.h>
#include <hip/hip_bf16.h>

#define N_NODES 10000
#define DIM 512
#define NCLS 64
#define BM 64
#define BN 128
#define BK 64
#define ELLW 64
#define GSLOTS 8

typedef __hip_bfloat16 bf16;
typedef unsigned short u16;
typedef __attribute__((ext_vector_type(8))) short short8;
typedef __attribute__((ext_vector_type(4))) float f32x4;

__device__ __forceinline__ float b2f(bf16 v) { return __bfloat162float(v); }
__device__ __forceinline__ float ldIn(const void* p, size_t i, int isb) {
    return isb ? b2f(((const bf16*)p)[i]) : ((const float*)p)[i];
}
__device__ __forceinline__ int getE(const int* ei, int is64, int flat) {
    return is64 ? ei[2 * (size_t)flat] : ei[flat];
}
__device__ __forceinline__ void load_lds16(const bf16* g, bf16* l) {
    __builtin_amdgcn_global_load_lds(
        (const __attribute__((address_space(1))) void*)g,
        (__attribute__((address_space(3))) void*)l, 16, 0, 0);
}

// ---- init: zero cursor; block 0 wave 0 sniffs dtypes ----
__global__ void init_kernel(const u16* x16, const int* ei, int* flags, int* cursor) {
    int i = blockIdx.x * blockDim.x + threadIdx.x;
    if (i < N_NODES + 64) cursor[i] = 0;   // +slack so gemm's deg reads are defined
    if (blockIdx.x == 0 && threadIdx.x < 64) {
        int l = threadIdx.x;
        int cf = 0;
        #pragma unroll
        for (int j = 0; j < 4; j++) {
            int e = (x16[l * 4 + j] >> 7) & 0xFF;
            cf += (e >= 97 && e <= 157) ? 1 : 0;
        }
        #pragma unroll
        for (int o = 32; o > 0; o >>= 1) cf += __shfl_xor(cf, o, 64);
        int cz = (l < 32) ? ((ei[2 * l + 1] == 0) ? 1 : 0) : 0;
        #pragma unroll
        for (int o = 32; o > 0; o >>= 1) cz += __shfl_xor(cz, o, 64);
        if (l == 0) { flags[0] = (cf >= 200) ? 1 : 0; flags[1] = (cz >= 16) ? 1 : 0; }
    }
}

// ---- fused: x->bf16 | 3 weight transposes | ELL build. One dispatch. ----
__global__ __launch_bounds__(256) void convert_all(
        const void* __restrict__ X, const void* __restrict__ W1,
        const void* __restrict__ W2, const void* __restrict__ Wc,
        const int* __restrict__ ei, const int* __restrict__ flags,
        int* __restrict__ cursor, int* __restrict__ ell,
        bf16* __restrict__ Xb, bf16* __restrict__ Wt1, bf16* __restrict__ Wt2,
        bf16* __restrict__ Wtc, int E) {
    __shared__ float tile[32][33];
    int b = blockIdx.x, t = threadIdx.x;
    if (b < 2500) {                      // x: 8 elems/thread
        int isb = flags[0];
        int base = (b * 256 + t) * 8;
        bf16 o[8];
        if (isb) {
            *(uint4*)o = *(const uint4*)((const bf16*)X + base);
        } else {
            const float* Xf = (const float*)X + base;
            float4 v0 = *(const float4*)Xf, v1 = *(const float4*)(Xf + 4);
            o[0] = __float2bfloat16(v0.x); o[1] = __float2bfloat16(v0.y);
            o[2] = __float2bfloat16(v0.z); o[3] = __float2bfloat16(v0.w);
            o[4] = __float2bfloat16(v1.x); o[5] = __float2bfloat16(v1.y);
            o[6] = __float2bfloat16(v1.z); o[7] = __float2bfloat16(v1.w);
        }
        *(uint4*)&Xb[base] = *(uint4*)o;
    } else if (b < 3044) {               // W[K][N] -> Wt[N][K]
        int isb = flags[0];
        const void* W; bf16* Wt; int N; int bb;
        if (b < 2756)      { W = W1; Wt = Wt1; N = DIM;  bb = b - 2500; }
        else if (b < 3012) { W = W2; Wt = Wt2; N = DIM;  bb = b - 2756; }
        else               { W = Wc; Wt = Wtc; N = NCLS; bb = b - 3012; }
        int nt = N / 32;
        int n0 = (bb % nt) * 32, k0 = (bb / nt) * 32;
        int tx = t & 31, ty = t >> 5;
        for (int r = ty; r < 32; r += 8)
            tile[r][tx] = ldIn(W, (size_t)(k0 + r) * N + n0 + tx, isb);
        __syncthreads();
        for (int r = ty; r < 32; r += 8)
            Wt[(size_t)(n0 + r) * DIM + k0 + tx] = __float2bfloat16(tile[tx][r]);
    } else {                             // ELL build
        int e = (b - 3044) * 256 + t;
        if (e >= E) return;
        int is64 = flags[1];
        int s = getE(ei, is64, e), d = getE(ei, is64, E + e);
        if (s == d || (unsigned)s >= N_NODES || (unsigned)d >= N_NODES) return;
        int pos = atomicAdd(&cursor[d], 1);
        ell[d * ELLW + (pos & (ELLW - 1))] = s;
    }
}

// ---- MFMA GEMM: C = (A @ Bt^T) * rsqrt(deg+1). 64x128 tile, BK=64.
//      Rows [M, 10048) are written as ZERO (gather's padding row lives there). ----
__global__ __launch_bounds__(256) void gemm_mfma(
        const bf16* __restrict__ A, const bf16* __restrict__ Bt,
        bf16* __restrict__ C, int M, int Nc, int K,
        const int* __restrict__ deg) {
    __shared__ bf16 At[BM * BK];    // 8 KB
    __shared__ bf16 Bts[BN * BK];   // 16 KB
    int t = threadIdx.x;
    int w = t >> 6, l = t & 63;
    int bm = blockIdx.y * BM, bn = blockIdx.x * BN;
    int wn = w * 32;

    f32x4 acc[4][2] = {};
    int srow8 = l >> 3;
    int sk8b  = (l & 7) * 8;

    for (int k0 = 0; k0 < K; k0 += BK) {
        __syncthreads();
        #pragma unroll
        for (int i = 0; i < 2; i++) {     // A: 8 chunks of 8 rows, 2/wave
            int c = w * 2 + i;
            load_lds16(A + (size_t)(bm + c * 8 + srow8) * K + k0 + sk8b, &At[c * 512]);
        }
        #pragma unroll
        for (int i = 0; i < 4; i++) {     // B: 16 chunks, 4/wave
            int c = w * 4 + i;
            load_lds16(Bt + (size_t)(bn + c * 8 + srow8) * K + k0 + sk8b, &Bts[c * 512]);
        }
        __syncthreads();

        #pragma unroll
        for (int kk = 0; kk < BK; kk += 32) {
            short8 af[4], bfr[2];
            #pragma unroll
            for (int i = 0; i < 4; i++)
                af[i] = *(const short8*)&At[(i * 16 + (l & 15)) * BK + kk + (l >> 4) * 8];
            #pragma unroll
            for (int j = 0; j < 2; j++)
                bfr[j] = *(const short8*)&Bts[(wn + j * 16 + (l & 15)) * BK + kk + (l >> 4) * 8];
            #pragma unroll
            for (int i = 0; i < 4; i++)
                #pragma unroll
                for (int j = 0; j < 2; j++)
                    acc[i][j] = __builtin_amdgcn_mfma_f32_16x16x32_bf16(
                                    af[i], bfr[j], acc[i][j], 0, 0, 0);
        }
    }

    // C/D map: col = lane&15, row = (lane>>4)*4 + reg
    int col = l & 15, rq = (l >> 4) * 4;
    #pragma unroll
    for (int i = 0; i < 4; i++) {
        #pragma unroll
        for (int r = 0; r < 4; r++) {
            int gm = bm + i * 16 + rq + r;
            float rs = (gm < M) ? rsqrtf((float)deg[gm] + 1.0f) : 0.0f;
            #pragma unroll
            for (int j = 0; j < 2; j++) {
                int gn = bn + wn + j * 16 + col;
                C[(size_t)gm * Nc + gn] = __float2bfloat16(acc[i][j][r] * rs);
            }
        }
    }
}

// ---- gather (ELL, LDS-staged): one wave per dst node. Each wave issues 8
//      async 1KB row-copies (global_load_lds, zero VGPR cost), waits vmcnt(0)
//      wave-locally, accumulates from LDS. Pad slots -> zero row N_NODES. ----
__global__ __launch_bounds__(256) void gather_lds(
        const int* __restrict__ cursor, const int* __restrict__ ell,
        const bf16* __restrict__ Hs, const void* __restrict__ bias,
        const int* __restrict__ flags, bf16* __restrict__ Out, int relu) {
    __shared__ bf16 stage[4 * GSLOTS * 512];   // 32 KB (8 KB per wave)
    int t = threadIdx.x, w = t >> 6, lane = t & 63;
    bf16* myst = stage + w * (GSLOTS * 512);
    int wid = (int)((blockIdx.x * (size_t)blockDim.x + t) >> 6);
    if (wid >= N_NODES) return;
    int cnt0 = cursor[wid];
    int cnt = min(cnt0, ELLW);
    int idx = ell[wid * ELLW + lane];   // lane i holds edge i

    float acc[8];
    bf16 v[8];
    *(uint4*)v = *(const uint4*)(Hs + (size_t)wid * DIM + lane * 8);   // self-loop
    #pragma unroll
    for (int j = 0; j < 8; j++) acc[j] = b2f(v[j]);

    for (int e = 0; e < cnt; e += GSLOTS) {
        __builtin_amdgcn_s_waitcnt(0xC07F);       // lgkmcnt(0): prior ds_reads done
        __builtin_amdgcn_sched_barrier(0);
        #pragma unroll
        for (int j = 0; j < GSLOTS; j++) {
            int s = __shfl(idx, (e + j) & 63, 64);
            s = (e + j < cnt) ? s : N_NODES;      // pad -> zero row (L1-hot)
            load_lds16(Hs + (size_t)s * DIM + lane * 8, myst + j * 512);
        }
        __builtin_amdgcn_s_waitcnt(0x3F70);       // vmcnt(0): rows landed in LDS
        __builtin_amdgcn_sched_barrier(0);
        #pragma unroll
        for (int j = 0; j < GSLOTS; j++) {
            bf16 r[8];
            *(uint4*)r = *(const uint4*)(myst + j * 512 + lane * 8);
            #pragma unroll
            for (int k = 0; k < 8; k++) acc[k] += b2f(r[k]);
        }
        __builtin_amdgcn_sched_barrier(0);
    }

    float ds = rsqrtf((float)cnt0 + 1.0f);
    int ibias = flags[0];
    bf16 o[8];
    #pragma unroll
    for (int j = 0; j < 8; j++) {
        float val = acc[j] * ds + ldIn(bias, lane * 8 + j, ibias);
        if (relu) val = fmaxf(val, 0.0f);
        o[j] = __float2bfloat16(val);
    }
    *(uint4*)(Out + (size_t)wid * DIM + lane * 8) = *(uint4*)o;
}

// ---- fused classifier + bias + log-softmax: one wave per 16 rows, no LDS ----
__global__ __launch_bounds__(64) void cls_lsm_kernel(
        const bf16* __restrict__ A, const bf16* __restrict__ Wct,
        const void* __restrict__ bias, const int* __restrict__ flags,
        float* __restrict__ out, int M) {
    int l = threadIdx.x;
    int row0 = blockIdx.x * 16;
    int q = l >> 4, col15 = l & 15;

    f32x4 acc[4] = {};
    #pragma unroll 4
    for (int k0 = 0; k0 < DIM; k0 += 32) {
        short8 af = *(const short8*)&A[(size_t)(row0 + col15) * DIM + k0 + q * 8];
        #pragma unroll
        for (int j = 0; j < 4; j++) {
            short8 bfr = *(const short8*)&Wct[(size_t)(j * 16 + col15) * DIM + k0 + q * 8];
            acc[j] = __builtin_amdgcn_mfma_f32_16x16x32_bf16(af, bfr, acc[j], 0, 0, 0);
        }
    }

    int ibias = flags[0];
    float bcol[4];
    #pragma unroll
    for (int j = 0; j < 4; j++) bcol[j] = ldIn(bias, j * 16 + col15, ibias);

    #pragma unroll
    for (int r = 0; r < 4; r++) {
        int row = row0 + q * 4 + r;
        float v[4];
        #pragma unroll
        for (int j = 0; j < 4; j++) v[j] = acc[j][r] + bcol[j];
        float m = fmaxf(fmaxf(v[0], v[1]), fmaxf(v[2], v[3]));
        #pragma unroll
        for (int o = 8; o > 0; o >>= 1) m = fmaxf(m, __shfl_xor(m, o, 64));
        float s = __expf(v[0] - m) + __expf(v[1] - m) + __expf(v[2] - m) + __expf(v[3] - m);
        #pragma unroll
        for (int o = 8; o > 0; o >>= 1) s += __shfl_xor(s, o, 64);
        float lse = m + __logf(s);
        if (row < M) {
            #pragma unroll
            for (int j = 0; j < 4; j++) {
                out[(size_t)row * NCLS + j * 16 + col15] = v[j];
                out[(size_t)M * NCLS + (size_t)row * NCLS + j * 16 + col15] = v[j] - lse;
            }
        }
    }
}

extern "C" void kernel_launch(void* const* d_in, const int* in_sizes, int n_in,
                              void* d_out, int out_size, void* d_ws, size_t ws_size,
                              hipStream_t stream) {
    const void* x  = d_in[0];
    const int*  ei = (const int*)d_in[1];
    const void* W1 = d_in[2];
    const void* b1 = d_in[3];
    const void* W2 = d_in[4];
    const void* b2 = d_in[5];
    const void* Wc = d_in[6];
    const void* bc = d_in[7];
    float* out = (float*)d_out;
    int E = in_sizes[1] / 2;

    // workspace layout (~38 MB; operand buffers padded to 10240 rows)
    char* ws = (char*)d_ws;
    int*   flags  = (int*)ws;                        // @0
    int*   cursor = (int*)(ws + 65536);              // 40 KB (+64 slack ints)
    int*   ell    = (int*)(ws + 131072);             // 2.56 MB
    bf16*  xb     = (bf16*) (ws + 4194304);          // 10240 rows x 512 bf16
    bf16*  Wt1    = (bf16*) (ws + 14680064);         // 512 KB
    bf16*  Wt2    = (bf16*) (ws + 15204352);         // 512 KB
    bf16*  Wct    = (bf16*) (ws + 15728640);         // 64 KB
    bf16*  B0     = (bf16*) (ws + 16777216);         // 10240 rows
    bf16*  B1     = (bf16*) (ws + 27262976);         // 10240 rows

    dim3 gg(DIM / BN, (N_NODES + BM - 1) / BM);      // (4, 157)
    int gN = (N_NODES * 64 + 255) / 256;             // 2500 blocks, 1 wave/node
    int gConv = 3044 + (E + 255) / 256;

    // ---- preamble: 2 dispatches ----
    init_kernel<<<(N_NODES + 64 + 255) / 256, 256, 0, stream>>>((const u16*)x, ei, flags, cursor);
    convert_all<<<gConv, 256, 0, stream>>>(x, W1, W2, Wc, ei, flags, cursor, ell,
                                           xb, Wt1, Wt2, Wct, E);

    // ---- layer 1 ----
    gemm_mfma<<<gg, 256, 0, stream>>>(xb, Wt1, B0, N_NODES, DIM, DIM, cursor);
    gather_lds<<<gN, 256, 0, stream>>>(cursor, ell, B0, b1, flags, B1, 1);

    // ---- layer 2 ----
    gemm_mfma<<<gg, 256, 0, stream>>>(B1, Wt2, B0, N_NODES, DIM, DIM, cursor);
    gather_lds<<<gN, 256, 0, stream>>>(cursor, ell, B0, b2, flags, B1, 0);

    // ---- fused classifier + log-softmax ----
    cls_lsm_kernel<<<(N_NODES + 15) / 16, 64, 0, stream>>>(B1, Wct, bc, flags, out, N_NODES);
}

// Round 13
// 191.872 us; speedup vs baseline: 1.0238x; 1.0238x over previous
//
#include <hip/hip_runtime.h>
#include <hip/hip_bf16.h>

#define N_NODES 10000
#define DIM 512
#define NCLS 64
#define BM 64
#define BN 128
#define BK 64
#define ELLW 64

typedef __hip_bfloat16 bf16;
typedef unsigned short u16;
typedef __attribute__((ext_vector_type(8))) short short8;
typedef __attribute__((ext_vector_type(4))) float f32x4;

__device__ __forceinline__ float b2f(bf16 v) { return __bfloat162float(v); }
__device__ __forceinline__ float ldIn(const void* p, size_t i, int isb) {
    return isb ? b2f(((const bf16*)p)[i]) : ((const float*)p)[i];
}
__device__ __forceinline__ int getE(const int* ei, int is64, int flat) {
    return is64 ? ei[2 * (size_t)flat] : ei[flat];
}
__device__ __forceinline__ void load_lds16(const bf16* g, bf16* l) {
    __builtin_amdgcn_global_load_lds(
        (const __attribute__((address_space(1))) void*)g,
        (__attribute__((address_space(3))) void*)l, 16, 0, 0);
}

// ---- init: zero cursor; block 0 wave 0 sniffs dtypes ----
__global__ void init_kernel(const u16* x16, const int* ei, int* flags, int* cursor) {
    int i = blockIdx.x * blockDim.x + threadIdx.x;
    if (i < N_NODES) cursor[i] = 0;
    if (blockIdx.x == 0 && threadIdx.x < 64) {
        int l = threadIdx.x;
        int cf = 0;
        #pragma unroll
        for (int j = 0; j < 4; j++) {
            int e = (x16[l * 4 + j] >> 7) & 0xFF;
            cf += (e >= 97 && e <= 157) ? 1 : 0;
        }
        #pragma unroll
        for (int o = 32; o > 0; o >>= 1) cf += __shfl_xor(cf, o, 64);
        int cz = (l < 32) ? ((ei[2 * l + 1] == 0) ? 1 : 0) : 0;
        #pragma unroll
        for (int o = 32; o > 0; o >>= 1) cz += __shfl_xor(cz, o, 64);
        if (l == 0) { flags[0] = (cf >= 200) ? 1 : 0; flags[1] = (cz >= 16) ? 1 : 0; }
    }
}

// ---- fused: x->bf16 | 3 weight transposes | ELL build. One dispatch. ----
__global__ __launch_bounds__(256) void convert_all(
        const void* __restrict__ X, const void* __restrict__ W1,
        const void* __restrict__ W2, const void* __restrict__ Wc,
        const int* __restrict__ ei, const int* __restrict__ flags,
        int* __restrict__ cursor, int* __restrict__ ell,
        bf16* __restrict__ Xb, bf16* __restrict__ Wt1, bf16* __restrict__ Wt2,
        bf16* __restrict__ Wtc, int E) {
    __shared__ float tile[32][33];
    int b = blockIdx.x, t = threadIdx.x;
    if (b < 2500) {                      // x: 8 elems/thread
        int isb = flags[0];
        int base = (b * 256 + t) * 8;
        bf16 o[8];
        if (isb) {
            *(uint4*)o = *(const uint4*)((const bf16*)X + base);
        } else {
            const float* Xf = (const float*)X + base;
            float4 v0 = *(const float4*)Xf, v1 = *(const float4*)(Xf + 4);
            o[0] = __float2bfloat16(v0.x); o[1] = __float2bfloat16(v0.y);
            o[2] = __float2bfloat16(v0.z); o[3] = __float2bfloat16(v0.w);
            o[4] = __float2bfloat16(v1.x); o[5] = __float2bfloat16(v1.y);
            o[6] = __float2bfloat16(v1.z); o[7] = __float2bfloat16(v1.w);
        }
        *(uint4*)&Xb[base] = *(uint4*)o;
    } else if (b < 3044) {               // W[K][N] -> Wt[N][K]
        int isb = flags[0];
        const void* W; bf16* Wt; int N; int bb;
        if (b < 2756)      { W = W1; Wt = Wt1; N = DIM;  bb = b - 2500; }
        else if (b < 3012) { W = W2; Wt = Wt2; N = DIM;  bb = b - 2756; }
        else               { W = Wc; Wt = Wtc; N = NCLS; bb = b - 3012; }
        int nt = N / 32;
        int n0 = (bb % nt) * 32, k0 = (bb / nt) * 32;
        int tx = t & 31, ty = t >> 5;
        for (int r = ty; r < 32; r += 8)
            tile[r][tx] = ldIn(W, (size_t)(k0 + r) * N + n0 + tx, isb);
        __syncthreads();
        for (int r = ty; r < 32; r += 8)
            Wt[(size_t)(n0 + r) * DIM + k0 + tx] = __float2bfloat16(tile[tx][r]);
    } else {                             // ELL build
        int e = (b - 3044) * 256 + t;
        if (e >= E) return;
        int is64 = flags[1];
        int s = getE(ei, is64, e), d = getE(ei, is64, E + e);
        if (s == d || (unsigned)s >= N_NODES || (unsigned)d >= N_NODES) return;
        int pos = atomicAdd(&cursor[d], 1);
        ell[d * ELLW + (pos & (ELLW - 1))] = s;
    }
}

// ---- MFMA GEMM: C = (A @ Bt^T) * rsqrt(deg+1). 64x128 tile, BK=64. ----
__global__ __launch_bounds__(256) void gemm_mfma(
        const bf16* __restrict__ A, const bf16* __restrict__ Bt,
        bf16* __restrict__ C, int M, int Nc, int K,
        const int* __restrict__ deg) {
    __shared__ bf16 At[BM * BK];    // 8 KB
    __shared__ bf16 Bts[BN * BK];   // 16 KB
    int t = threadIdx.x;
    int w = t >> 6, l = t & 63;
    int bm = blockIdx.y * BM, bn = blockIdx.x * BN;
    int wn = w * 32;

    f32x4 acc[4][2] = {};
    int srow8 = l >> 3;          // 0..7 within 8-row chunk
    int sk8b  = (l & 7) * 8;     // k-offset of this lane's 16B

    for (int k0 = 0; k0 < K; k0 += BK) {
        __syncthreads();
        #pragma unroll
        for (int i = 0; i < 2; i++) {     // A: 8 chunks of 8 rows, 2/wave
            int c = w * 2 + i;
            load_lds16(A + (size_t)(bm + c * 8 + srow8) * K + k0 + sk8b, &At[c * 512]);
        }
        #pragma unroll
        for (int i = 0; i < 4; i++) {     // B: 16 chunks, 4/wave
            int c = w * 4 + i;
            load_lds16(Bt + (size_t)(bn + c * 8 + srow8) * K + k0 + sk8b, &Bts[c * 512]);
        }
        __syncthreads();

        #pragma unroll
        for (int kk = 0; kk < BK; kk += 32) {
            short8 af[4], bfr[2];
            #pragma unroll
            for (int i = 0; i < 4; i++)
                af[i] = *(const short8*)&At[(i * 16 + (l & 15)) * BK + kk + (l >> 4) * 8];
            #pragma unroll
            for (int j = 0; j < 2; j++)
                bfr[j] = *(const short8*)&Bts[(wn + j * 16 + (l & 15)) * BK + kk + (l >> 4) * 8];
            #pragma unroll
            for (int i = 0; i < 4; i++)
                #pragma unroll
                for (int j = 0; j < 2; j++)
                    acc[i][j] = __builtin_amdgcn_mfma_f32_16x16x32_bf16(
                                    af[i], bfr[j], acc[i][j], 0, 0, 0);
        }
    }

    // C/D map: col = lane&15, row = (lane>>4)*4 + reg
    int col = l & 15, rq = (l >> 4) * 4;
    #pragma unroll
    for (int i = 0; i < 4; i++) {
        #pragma unroll
        for (int r = 0; r < 4; r++) {
            int gm = bm + i * 16 + rq + r;
            if (gm >= M) continue;
            float rs = rsqrtf((float)deg[gm] + 1.0f);
            #pragma unroll
            for (int j = 0; j < 2; j++) {
                int gn = bn + wn + j * 16 + col;
                C[(size_t)gm * Nc + gn] = __float2bfloat16(acc[i][j][r] * rs);
            }
        }
    }
}

// ---- gather (ELL): one wave per dst; indices in wave registers; 8-deep MLP ----
__global__ __launch_bounds__(256) void gather_ell(
        const int* __restrict__ cursor, const int* __restrict__ ell,
        const bf16* __restrict__ Hs, const void* __restrict__ bias,
        const int* __restrict__ flags, bf16* __restrict__ Out, int relu) {
    int wid = (int)((blockIdx.x * (size_t)blockDim.x + threadIdx.x) >> 6);
    int lane = threadIdx.x & 63;
    if (wid >= N_NODES) return;
    int cnt0 = cursor[wid];
    int cnt = min(cnt0, ELLW);
    int idx = ell[wid * ELLW + lane];   // lane i holds edge i

    float acc[8];
    bf16 v[8];
    *(uint4*)v = *(const uint4*)(Hs + (size_t)wid * DIM + lane * 8);   // self-loop
    #pragma unroll
    for (int j = 0; j < 8; j++) acc[j] = b2f(v[j]);

    int e = 0;
    for (; e + 7 < cnt; e += 8) {
        bf16 r[8][8];
        #pragma unroll
        for (int b = 0; b < 8; b++) {
            int s = __shfl(idx, e + b, 64);
            *(uint4*)r[b] = *(const uint4*)(Hs + (size_t)s * DIM + lane * 8);
        }
        #pragma unroll
        for (int j = 0; j < 8; j++)
            acc[j] += ((b2f(r[0][j]) + b2f(r[1][j])) + (b2f(r[2][j]) + b2f(r[3][j])))
                    + ((b2f(r[4][j]) + b2f(r[5][j])) + (b2f(r[6][j]) + b2f(r[7][j])));
    }
    for (; e < cnt; e++) {
        int s = __shfl(idx, e, 64);
        *(uint4*)v = *(const uint4*)(Hs + (size_t)s * DIM + lane * 8);
        #pragma unroll
        for (int j = 0; j < 8; j++) acc[j] += b2f(v[j]);
    }

    float ds = rsqrtf((float)cnt0 + 1.0f);
    int ibias = flags[0];
    bf16 o[8];
    #pragma unroll
    for (int j = 0; j < 8; j++) {
        float val = acc[j] * ds + ldIn(bias, lane * 8 + j, ibias);
        if (relu) val = fmaxf(val, 0.0f);
        o[j] = __float2bfloat16(val);
    }
    *(uint4*)(Out + (size_t)wid * DIM + lane * 8) = *(uint4*)o;
}

// ---- fused classifier + bias + log-softmax: one wave per 16 rows, no LDS ----
__global__ __launch_bounds__(64) void cls_lsm_kernel(
        const bf16* __restrict__ A, const bf16* __restrict__ Wct,
        const void* __restrict__ bias, const int* __restrict__ flags,
        float* __restrict__ out, int M) {
    int l = threadIdx.x;
    int row0 = blockIdx.x * 16;
    int q = l >> 4, col15 = l & 15;

    f32x4 acc[4] = {};
    #pragma unroll 4
    for (int k0 = 0; k0 < DIM; k0 += 32) {
        short8 af = *(const short8*)&A[(size_t)(row0 + col15) * DIM + k0 + q * 8];
        #pragma unroll
        for (int j = 0; j < 4; j++) {
            short8 bfr = *(const short8*)&Wct[(size_t)(j * 16 + col15) * DIM + k0 + q * 8];
            acc[j] = __builtin_amdgcn_mfma_f32_16x16x32_bf16(af, bfr, acc[j], 0, 0, 0);
        }
    }

    int ibias = flags[0];
    float bcol[4];
    #pragma unroll
    for (int j = 0; j < 4; j++) bcol[j] = ldIn(bias, j * 16 + col15, ibias);

    #pragma unroll
    for (int r = 0; r < 4; r++) {
        int row = row0 + q * 4 + r;
        float v[4];
        #pragma unroll
        for (int j = 0; j < 4; j++) v[j] = acc[j][r] + bcol[j];
        float m = fmaxf(fmaxf(v[0], v[1]), fmaxf(v[2], v[3]));
        #pragma unroll
        for (int o = 8; o > 0; o >>= 1) m = fmaxf(m, __shfl_xor(m, o, 64));
        float s = __expf(v[0] - m) + __expf(v[1] - m) + __expf(v[2] - m) + __expf(v[3] - m);
        #pragma unroll
        for (int o = 8; o > 0; o >>= 1) s += __shfl_xor(s, o, 64);
        float lse = m + __logf(s);
        if (row < M) {
            #pragma unroll
            for (int j = 0; j < 4; j++) {
                out[(size_t)row * NCLS + j * 16 + col15] = v[j];
                out[(size_t)M * NCLS + (size_t)row * NCLS + j * 16 + col15] = v[j] - lse;
            }
        }
    }
}

extern "C" void kernel_launch(void* const* d_in, const int* in_sizes, int n_in,
                              void* d_out, int out_size, void* d_ws, size_t ws_size,
                              hipStream_t stream) {
    const void* x  = d_in[0];
    const int*  ei = (const int*)d_in[1];
    const void* W1 = d_in[2];
    const void* b1 = d_in[3];
    const void* W2 = d_in[4];
    const void* b2 = d_in[5];
    const void* Wc = d_in[6];
    const void* bc = d_in[7];
    float* out = (float*)d_out;
    int E = in_sizes[1] / 2;

    // workspace layout (~38 MB; operand buffers padded to 10240 rows)
    char* ws = (char*)d_ws;
    int*   flags  = (int*)ws;                        // @0
    int*   cursor = (int*)(ws + 65536);              // 40 KB
    int*   ell    = (int*)(ws + 131072);             // 2.56 MB
    bf16*  xb     = (bf16*) (ws + 4194304);          // 10240 rows x 512 bf16
    bf16*  Wt1    = (bf16*) (ws + 14680064);         // 512 KB
    bf16*  Wt2    = (bf16*) (ws + 15204352);         // 512 KB
    bf16*  Wct    = (bf16*) (ws + 15728640);         // 64 KB
    bf16*  B0     = (bf16*) (ws + 16777216);         // 10240 rows
    bf16*  B1     = (bf16*) (ws + 27262976);         // 10240 rows

    int gN = (N_NODES * 64 + 255) / 256;
    dim3 gg(DIM / BN, (N_NODES + BM - 1) / BM);      // (4, 157)
    int gConv = 3044 + (E + 255) / 256;

    // ---- preamble: 2 dispatches ----
    init_kernel<<<(N_NODES + 255) / 256, 256, 0, stream>>>((const u16*)x, ei, flags, cursor);
    convert_all<<<gConv, 256, 0, stream>>>(x, W1, W2, Wc, ei, flags, cursor, ell,
                                           xb, Wt1, Wt2, Wct, E);

    // ---- layer 1 ----
    gemm_mfma<<<gg, 256, 0, stream>>>(xb, Wt1, B0, N_NODES, DIM, DIM, cursor);
    gather_ell<<<gN, 256, 0, stream>>>(cursor, ell, B0, b1, flags, B1, 1);

    // ---- layer 2 ----
    gemm_mfma<<<gg, 256, 0, stream>>>(B1, Wt2, B0, N_NODES, DIM, DIM, cursor);
    gather_ell<<<gN, 256, 0, stream>>>(cursor, ell, B0, b2, flags, B1, 0);

    // ---- fused classifier + log-softmax ----
    cls_lsm_kernel<<<(N_NODES + 15) / 16, 64, 0, stream>>>(B1, Wct, bc, flags, out, N_NODES);
}